// Round 8
// baseline (391.100 us; speedup 1.0000x reference)
//
#include <hip/hip_runtime.h>
#include <stdint.h>
#include <stddef.h>

#define M_DIM 8192
#define N_DIM 4096
#define K_DIM 4096

#define BM 128
#define BN 128
#define BK 128   // int8: 128 rows x 128 bytes = 16 KiB per operand tile

typedef int i32x4 __attribute__((ext_vector_type(4)));

__device__ __forceinline__ void async_load16(void* lds, const void* g) {
  __builtin_amdgcn_global_load_lds(
      (const __attribute__((address_space(1))) void*)g,
      (__attribute__((address_space(3))) void*)lds,
      16, 0, 0);
}

// R10 fused aux: quant_x (blocks [0,8192)) + pack_w (blocks [8192,12288)).
// UNCHANGED (control; did not surface in top-5 => combined < ~134 us).
__global__ void fused_aux_kernel(const float* __restrict__ x,
                                 signed char* __restrict__ xq,
                                 float* __restrict__ xs,
                                 const int* __restrict__ w,
                                 signed char* __restrict__ wp) {
  const int t = threadIdx.x;
  if (blockIdx.x < M_DIM) {
    const int row = blockIdx.x;
    const float4* xr = (const float4*)(x + (size_t)row * K_DIM);
    float4 v[4];
    float m = 0.f;
#pragma unroll
    for (int r = 0; r < 4; ++r) {
      v[r] = xr[r * 256 + t];                       // coalesced 16B/lane
      m = fmaxf(m, fmaxf(fmaxf(fabsf(v[r].x), fabsf(v[r].y)),
                         fmaxf(fabsf(v[r].z), fabsf(v[r].w))));
    }
#pragma unroll
    for (int off = 32; off > 0; off >>= 1)
      m = fmaxf(m, __shfl_down(m, off, 64));
    __shared__ float wmax[4];
    if ((t & 63) == 0) wmax[t >> 6] = m;
    __syncthreads();
    float rowmax = fmaxf(fmaxf(wmax[0], wmax[1]), fmaxf(wmax[2], wmax[3]));
    float inv = rowmax > 0.f ? 127.0f / rowmax : 0.f;
    if (t == 0) xs[row] = rowmax > 0.f ? rowmax * (1.0f / 127.0f) : 0.f;
    uint* oq = (uint*)(xq + (size_t)row * K_DIM);
#pragma unroll
    for (int r = 0; r < 4; ++r) {
      union { signed char c[4]; uint u; } o;
      o.c[0] = (signed char)(int)rintf(v[r].x * inv);
      o.c[1] = (signed char)(int)rintf(v[r].y * inv);
      o.c[2] = (signed char)(int)rintf(v[r].z * inv);
      o.c[3] = (signed char)(int)rintf(v[r].w * inv);
      oq[r * 256 + t] = o.u;                        // coalesced 4B/lane
    }
  } else {
    const int4* wi = (const int4*)w;
    uint* wo = (uint*)wp;
    size_t base = (size_t)(blockIdx.x - M_DIM) * 1024 + t;   // int4-chunk idx
#pragma unroll
    for (int r = 0; r < 4; ++r) {
      int4 a = wi[base + r * 256];
      union { signed char c[4]; uint u; } o;
      o.c[0] = (signed char)a.x; o.c[1] = (signed char)a.y;
      o.c[2] = (signed char)a.z; o.c[3] = (signed char)a.w;
      wo[base + r * 256] = o.u;
    }
  }
}

// C[M,N] = sum_k Aq[m,k]*Bq[n,k] * xs[m] * scaler[n], int8 MFMA 16x16x64.
// R12: {prefetch x residency} joint test. Evidence matrix so far:
//   {no-prefetch, 12 waves/CU} = 134 us (R0/R6)
//   {prefetch,     8 waves/CU} = 167 us (R3: 64KiB dbuf @ 256thr)
//   {no-prefetch,  8 waves/CU} = 134 us (R7) -> DS-pipe model falsified,
//     residency is the dominant term.
// This round reaches the untested cell {prefetch, 16 waves/CU}: 512-thread
// block, BM=BN=128, double-buffered (64 KiB LDS -> 2 blocks/CU = 16 waves,
// 4/SIMD). Wave tile 64x32 (acc[4][2], 8 waves as 2x4). Schedule is R3's
// correctness-proven one: stage next into buf^1, compute buf[cur], one
// __syncthreads per K-step (its vmcnt(0)+lgkmcnt(0) drain is the handoff).
// Read geometry per instruction is EXACTLY the empirically-0-conflict R0
// pattern (16 consecutive rows x 4 quad-chunks, 128B row stride,
// ck^(r&7) chunk swizzle) — swizzle theory retired after R4/R5.
__global__ __launch_bounds__(512, 4) void gemm_i8(
    const signed char* __restrict__ Aq, const signed char* __restrict__ Bq,
    const float* __restrict__ xs, const float* __restrict__ scaler,
    float* __restrict__ C) {
  __shared__ __align__(16) uint8_t sA[2][BM * BK];  // 2 x 16 KiB
  __shared__ __align__(16) uint8_t sB[2][BN * BK];  // 2 x 16 KiB

  // XCD-grouped mapping (as R0/R6): 2048 blocks = 8 xcd x 256 slots.
  const int bid  = blockIdx.x;
  const int xcd  = bid & 7;
  const int slot = bid >> 3;
  const int tile_n = (xcd * 4 + (slot & 3)) * BN;
  const int tile_m = (slot >> 2) * BM;

  const int tid  = threadIdx.x;
  const int w    = tid >> 6;         // 0..7
  const int lane = tid & 63;
  const int q    = lane >> 4;
  const int m16  = lane & 15;
  const int wrow = (w >> 2) * 64;    // 2 wave-rows of 64
  const int wcol = (w & 3) * 32;     // 4 wave-cols of 32

  // Staging: 1024 16B-chunks per operand, 512 threads -> 2 rounds each.
  // Slot g: r = g>>3, c = (g&7) ^ (r&7); LDS dest = wave-uniform base +
  // lane*16 (global_load_lds constraint); kt-invariant offsets hoisted.
  int g_off[2];
  size_t a_off[2], b_off[2];
#pragma unroll
  for (int p = 0; p < 2; ++p) {
    int g = p * 512 + tid;
    int r = g >> 3;
    int c = (g & 7) ^ (r & 7);
    g_off[p] = g * 16;
    a_off[p] = (size_t)(tile_m + r) * K_DIM + c * 16;
    b_off[p] = (size_t)(tile_n + r) * K_DIM + c * 16;
  }

  i32x4 acc[4][2];
#pragma unroll
  for (int i = 0; i < 4; ++i)
#pragma unroll
    for (int j = 0; j < 2; ++j)
      acc[i][j] = (i32x4){0, 0, 0, 0};

  // Prologue: stage kt=0 into buffer 0.
#pragma unroll
  for (int p = 0; p < 2; ++p) {
    async_load16(sA[0] + g_off[p], Aq + a_off[p]);
    async_load16(sB[0] + g_off[p], Bq + b_off[p]);
  }
  __syncthreads();   // vmcnt(0): buf0 ready

  int cur = 0;
  for (int kt = 0; kt < K_DIM; kt += BK) {
    // Phase 1: issue next tile's loads into buf^1 (in flight across compute).
    if (kt + BK < K_DIM) {
      const uint8_t* nA = (const uint8_t*)Aq + (kt + BK);
      const uint8_t* nB = (const uint8_t*)Bq + (kt + BK);
#pragma unroll
      for (int p = 0; p < 2; ++p) {
        async_load16(sA[cur ^ 1] + g_off[p], nA + a_off[p]);
        async_load16(sB[cur ^ 1] + g_off[p], nB + b_off[p]);
      }
    }

    // Phase 2: compute from buf[cur].
    const uint8_t* cA = sA[cur];
    const uint8_t* cB = sB[cur];
#pragma unroll
    for (int ks = 0; ks < 2; ++ks) {
      const int ck = (ks << 2) + q;   // chunk 0..7 = K bytes [ck*16, +16)
      i32x4 af[4], bfr[2];
#pragma unroll
      for (int t = 0; t < 4; ++t) {
        int ra = wrow + t * 16 + m16;
        af[t] = *(const i32x4*)(cA + (size_t)(((ra << 3) + (ck ^ (ra & 7))) << 4));
      }
#pragma unroll
      for (int t = 0; t < 2; ++t) {
        int rb = wcol + t * 16 + m16;
        bfr[t] = *(const i32x4*)(cB + (size_t)(((rb << 3) + (ck ^ (rb & 7))) << 4));
      }
#pragma unroll
      for (int i = 0; i < 4; ++i)
#pragma unroll
        for (int j = 0; j < 2; ++j)
          acc[i][j] = __builtin_amdgcn_mfma_i32_16x16x64_i8(
              af[i], bfr[j], acc[i][j], 0, 0, 0);
    }

    // One barrier per K-step: drains this step's prefetch (vmcnt(0)) and
    // all waves' LDS reads (lgkmcnt(0)); then buf^1 becomes current.
    __syncthreads();
    cur ^= 1;
  }

  // Epilogue: C/D col=lane&15, row=(lane>>4)*4+reg (verified layout).
  float rs[4][4];
#pragma unroll
  for (int i = 0; i < 4; ++i)
#pragma unroll
    for (int r = 0; r < 4; ++r)
      rs[i][r] = xs[tile_m + wrow + i * 16 + q * 4 + r];
#pragma unroll
  for (int j = 0; j < 2; ++j) {
    int col = tile_n + wcol + j * 16 + m16;
    float s = scaler[col];
#pragma unroll
    for (int i = 0; i < 4; ++i) {
      int row0 = tile_m + wrow + i * 16 + q * 4;
#pragma unroll
      for (int r = 0; r < 4; ++r)
        C[(size_t)(row0 + r) * N_DIM + col] = (float)acc[i][j][r] * rs[i][r] * s;
    }
  }
}

// Correct-but-slow insurance if ws_size is too small.
__global__ void fallback_kernel(const float* __restrict__ x,
                                const int* __restrict__ wq,
                                const float* __restrict__ s,
                                float* __restrict__ out) {
  size_t idx = (size_t)blockIdx.x * blockDim.x + threadIdx.x;
  int m = (int)(idx / N_DIM), n = (int)(idx % N_DIM);
  const float* xr = x + (size_t)m * K_DIM;
  const int* wr = wq + (size_t)n * K_DIM;
  float acc = 0.f;
  for (int k = 0; k < K_DIM; ++k) acc += xr[k] * (float)wr[k];
  out[idx] = acc * s[n];
}

extern "C" void kernel_launch(void* const* d_in, const int* in_sizes, int n_in,
                              void* d_out, int out_size, void* d_ws, size_t ws_size,
                              hipStream_t stream) {
  const float* x = (const float*)d_in[0];
  const int* wq = (const int*)d_in[1];   // int32 (verified R2)
  const float* sc = (const float*)d_in[2];
  float* out = (float*)d_out;

  const size_t nx = (size_t)M_DIM * K_DIM;   // 33,554,432
  const size_t nw = (size_t)N_DIM * K_DIM;   // 16,777,216
  const size_t off_xq = 32768;               // xs: 8192 floats
  const size_t off_wp = off_xq + nx;
  const size_t need = off_wp + nw;           // ~50.4 MB

  if (ws_size < need) {
    size_t total = (size_t)M_DIM * N_DIM;
    fallback_kernel<<<(int)(total / 256), 256, 0, stream>>>(x, wq, sc, out);
    return;
  }

  float* xs = (float*)d_ws;
  signed char* xq = (signed char*)d_ws + off_xq;
  signed char* wp = (signed char*)d_ws + off_wp;

  // One fused aux dispatch: 8192 quant blocks + 4096 pack blocks.
  fused_aux_kernel<<<M_DIM + (int)(nw / 4 / 1024), 256, 0, stream>>>(
      x, xq, xs, wq, wp);

  // 64 x 32 = 2048 tiles of 128x128, 512 threads (8 waves) each.
  gemm_i8<<<(N_DIM / BN) * (M_DIM / BM), 512, 0, stream>>>(xq, wp, xs, sc, out);
}